// Round 6
// baseline (360.620 us; speedup 1.0000x reference)
//
#include <hip/hip_runtime.h>
#include <cstdint>
#include <cstddef>

// ============================================================================
// MechanismGrabber on MI355X (gfx950)
//
// selected[n,d] = sum_{m,e} a[n,m]*x[n,e]*Wm[m,d,e] + sum_m a[n,m]*(bm+cm)[m,d]
// == single GEMM: (N=32768) x (K=16448) x (D=256) with A generated on the fly.
//
// R5: 4 independent blocks/CU (128thr, 2 waves, tile 128x64), LDS exactly
//     40KB (3x8KB Wcat ring + 16KB a-tile in conflict-free [g][row][8] layout),
//     af computed pre-barrier (register-only, overlaps the vmcnt wait),
//     a-scalar reads are lgkm-only (vmcnt stream = staging, clean vmcnt(4)),
//     XCD swizzle pins one 2.1MB Wcat col-quarter per XCD (L2-resident).
// ============================================================================

typedef _Float16 f16;
typedef f16 f16x8 __attribute__((ext_vector_type(8)));
typedef float f32x4 __attribute__((ext_vector_type(4)));
typedef float f32x16 __attribute__((ext_vector_type(16)));

#define DEV __device__ __forceinline__

DEV uint32_t swz128(uint32_t b) { return b ^ (((b >> 7) & 7u) << 4); }

DEV void gload_lds16(const void* g, void* l) {
  __builtin_amdgcn_global_load_lds(
      (const __attribute__((address_space(1))) unsigned int*)g,
      (__attribute__((address_space(3))) unsigned int*)l, 16, 0, 0);
}

DEV f16x8 cvt8(float4 u0, float4 u1) {
  f16x8 v = {(f16)u0.x, (f16)u0.y, (f16)u0.z, (f16)u0.w,
             (f16)u1.x, (f16)u1.y, (f16)u1.z, (f16)u1.w};
  return v;
}

// ---------------------------------------------------------------------------
// prep for gemm_tpl (16x16x32 path, selector/integrate): unchanged.
// ---------------------------------------------------------------------------
__global__ void prep_b_kernel(const float* __restrict__ S, f16* __restrict__ dst,
                              int K, int BN, int total) {
  int t = blockIdx.x * 256 + threadIdx.x;
  if (t >= total) return;
  int gpc = BN * 8;
  int g = t % gpc;
  int c = (t / gpc) % (K / 64);
  int cb = t / (gpc * (K / 64));
  int ks = g / (BN * 4);
  int rem = g % (BN * 4);
  int col = rem >> 2;
  int kg = rem & 3;
  int J = cb * BN + col;
  int k = c * 64 + ks * 32 + kg * 8;
  const float* s = S + (size_t)J * K + k;
  float4 u0 = *(const float4*)s;
  float4 u1 = *(const float4*)(s + 4);
  f16* chunk = dst + (size_t)(cb * (K / 64) + c) * (BN * 64);
  *(f16x8*)((char*)chunk + swz128((uint32_t)g * 16)) = cvt8(u0, u1);
}

// ---------------------------------------------------------------------------
// Wcat v3: [cb 0..3][c 0..259] sub-chunks of 64k x 64col = 8 KB (linear,
// conflict-free). group g = kstep*128 + khalf*64 + col64, byte g*16, holds
// B[k][col] for k = kstep*16 + khalf*8 + (0..7), col = cb*64 + col64.
// c<256: er=c>>6, m=c&63; value[k][col] = Wm[m][col][er*64+k].
// c==256: value[k][col] = bm[k][col]+cm[k][col].  c>=257: dummy.
// ---------------------------------------------------------------------------
__global__ void prep_wcat_kernel(const float* __restrict__ Wm,
                                 const float* __restrict__ bm,
                                 const float* __restrict__ cm,
                                 f16* __restrict__ dst) {
  int t = blockIdx.x * 256 + threadIdx.x;
  if (t >= 4 * 257 * 512) return;
  int g = t & 511;
  int gc = t >> 9;
  int c = gc % 257;
  int cb = gc / 257;
  int kstep = g >> 7;          // 0..3
  int khalf = (g >> 6) & 1;    // 0..1
  int col = cb * 64 + (g & 63);
  int k0 = kstep * 16 + khalf * 8;
  f16x8 v;
  if (c < 256) {
    int m = c & 63;
    int e0 = (c >> 6) * 64 + k0;
    const float* s = Wm + ((size_t)m * 256 + col) * 256 + e0;
    float4 u0 = *(const float4*)s;
    float4 u1 = *(const float4*)(s + 4);
    v = cvt8(u0, u1);
  } else {
#pragma unroll
    for (int j = 0; j < 8; ++j) {
      int k = k0 + j;
      v[j] = (f16)(bm[k * 256 + col] + cm[k * 256 + col]);
    }
  }
  *(f16x8*)(dst + ((size_t)(cb * 260 + c)) * 4096 + (size_t)g * 8) = v;
}

// ---------------------------------------------------------------------------
// Generic MFMA GEMM (selector + integrate phases). Unchanged.
// ---------------------------------------------------------------------------
template <int BN, int NCHUNK, int A0C, int EPI>
__global__ __launch_bounds__(BN == 256 ? 512 : 256, 2)
void gemm_tpl(const float* __restrict__ A0, int lda0,
              const f16* __restrict__ A1, int lda1,
              const f16* __restrict__ Bt,
              const float* __restrict__ bias,
              float* __restrict__ outF, f16* __restrict__ outH, int ldo) {
  constexpr int WAVES = (BN == 256) ? 8 : 4;
  constexpr int THREADS = WAVES * 64;
  constexpr int WC = (BN == 256) ? 4 : 1;
  constexpr int WR = WAVES / WC;
  constexpr int RT = 128 / (WR * 16);
  constexpr int CT = (BN / WC) / 16;

  __shared__ alignas(16) f16 sA[2][128 * 64];
  __shared__ alignas(16) f16 sB[2][BN * 64];

  const int tid = threadIdx.x;
  const int lane = tid & 63;
  const int wid = tid >> 6;
  const int wr = wid / WC, wc = wid % WC;
  const int rb = blockIdx.x, cb = blockIdx.y;

  auto stageB = [&](int c, int buf) {
    const char* src = (const char*)(Bt + (size_t)(cb * NCHUNK + c) * (BN * 64));
#pragma unroll
    for (int it = 0; it < (BN * 64 * 2) / (THREADS * 16); ++it) {
      int off = (it * THREADS + tid) * 16;
      gload_lds16(src + off, (char*)&sB[buf][0] + off);
    }
  };
  auto stageA = [&](int c, int buf) {
#pragma unroll
    for (int it = 0; it < 1024 / THREADS; ++it) {
      int gg = it * THREADS + tid;
      int row = gg >> 3, eg = gg & 7;
      size_t rowG = (size_t)rb * 128 + row;
      f16x8 v;
      if (A0C > 0 && c < A0C) {
        const float* s = A0 + rowG * lda0 + c * 64 + eg * 8;
        float4 u0 = *(const float4*)s;
        float4 u1 = *(const float4*)(s + 4);
        v = cvt8(u0, u1);
      } else {
        v = *(const f16x8*)(A1 + rowG * lda1 + (c - A0C) * 64 + eg * 8);
      }
      *(f16x8*)((char*)&sA[buf][0] + swz128((uint32_t)(row * 128 + eg * 16))) = v;
    }
  };

  f32x4 acc[RT][CT];
#pragma unroll
  for (int i = 0; i < RT; ++i)
#pragma unroll
    for (int j = 0; j < CT; ++j) acc[i][j] = (f32x4){0.f, 0.f, 0.f, 0.f};

  stageB(0, 0);
  stageA(0, 0);
  __syncthreads();

  for (int c = 0; c < NCHUNK; ++c) {
    int cur = c & 1;
    if (c + 1 < NCHUNK) {
      stageB(c + 1, cur ^ 1);
      stageA(c + 1, cur ^ 1);
    }
#pragma unroll
    for (int ks = 0; ks < 2; ++ks) {
      f16x8 af[RT], bf[CT];
#pragma unroll
      for (int rt = 0; rt < RT; ++rt) {
        int row = wr * (RT * 16) + rt * 16 + (lane & 15);
        af[rt] = *(const f16x8*)((const char*)&sA[cur][0] +
                                 swz128((uint32_t)(row * 128 + ks * 64 + (lane >> 4) * 16)));
      }
#pragma unroll
      for (int ct = 0; ct < CT; ++ct) {
        int col = wc * (CT * 16) + ct * 16 + (lane & 15);
        bf[ct] = *(const f16x8*)((const char*)&sB[cur][0] +
                                 swz128((uint32_t)(((ks * BN + col) * 4 + (lane >> 4)) * 16)));
      }
#pragma unroll
      for (int rt = 0; rt < RT; ++rt)
#pragma unroll
        for (int ct = 0; ct < CT; ++ct)
          acc[rt][ct] = __builtin_amdgcn_mfma_f32_16x16x32_f16(af[rt], bf[ct], acc[rt][ct], 0, 0, 0);
    }
    __syncthreads();
  }

#pragma unroll
  for (int rt = 0; rt < RT; ++rt)
#pragma unroll
    for (int ct = 0; ct < CT; ++ct)
#pragma unroll
      for (int i = 0; i < 4; ++i) {
        size_t row = (size_t)rb * 128 + wr * (RT * 16) + rt * 16 + (lane >> 4) * 4 + i;
        int colG = cb * BN + wc * (CT * 16) + ct * 16 + (lane & 15);
        float v = acc[rt][ct][i];
        if constexpr (EPI == 0) {
          if (bias) v += bias[colG];
          outF[row * ldo + colG] = v;
        } else {
          v += bias[colG];
          float ge = 0.5f * v * (1.0f + erff(v * 0.70710678118f));
          outH[row * ldo + colG] = (f16)ge;
        }
      }
}

// ---------------------------------------------------------------------------
// selector finish: a16s in big_gemm's staging layout:
// a16s[rb6][g][row][j]  (rb6 = n>>7, row = n&127, m = g*8+j), 8KB per rb6.
// ---------------------------------------------------------------------------
__global__ void selector_finish(const float* __restrict__ logits,
                                const float* __restrict__ glog,
                                const float* __restrict__ b2,
                                const float* __restrict__ vm,
                                f16* __restrict__ a16s) {
  int n = blockIdx.x * 4 + (threadIdx.x >> 6);
  int m = threadIdx.x & 63;
  float l = logits[(size_t)n * 64 + m] + b2[m];
  float mx = l;
#pragma unroll
  for (int o = 32; o; o >>= 1) mx = fmaxf(mx, __shfl_xor(mx, o));
  float p = expf(l - mx);
  float s = p;
#pragma unroll
  for (int o = 32; o; o >>= 1) s += __shfl_xor(s, o);
  float g = glog[(size_t)n * 64 + m] + vm[m];
  float gate = 1.0f / (1.0f + expf(-g));
  int rb6 = n >> 7, row = n & 127, gg = m >> 3, j = m & 7;
  a16s[(size_t)rb6 * 8192 + gg * 1024 + row * 8 + j] = (f16)(p / s * gate);
}

// ---------------------------------------------------------------------------
// big_gemm v5: 128 threads (2 waves), tile 128x64, wave tile 64x64
// (32x32x16, rt=2, ct=2). 3x8KB ring + 16KB a-tile = 40KB -> 4 blocks/CU.
// Per iter q: stage(q+2,p2) -> af(q) [reg-only, pre-barrier] -> vmcnt(4)
// -> barrier -> ds_read bf(q+1) from p1 -> 16 MFMA(q) -> rotate.
// XCD swizzle: cb=(bid&7)>>1, rb=(bid&1)*128+(bid>>3).
// ---------------------------------------------------------------------------
__global__ __launch_bounds__(128, 2)
void big_gemm(const float* __restrict__ x, const f16* __restrict__ a16s,
              const f16* __restrict__ Wcat, f16* __restrict__ sel) {
  __shared__ alignas(16) f16 sB[3][64 * 64];     // 3 x 8 KB ring
  __shared__ alignas(16) f16 sAa[8 * 128 * 8];   // 16 KB: [g][row][8m]

  const int tid = threadIdx.x;
  const int lane = tid & 63;
  const int wid = tid >> 6;        // 0..1
  const int l31 = lane & 31;
  const int khalf = lane >> 5;     // 0..1
  const int bid = blockIdx.x;
  const int xcd = bid & 7;
  const int cb = xcd >> 1;                     // col-quarter, fixed per XCD-pair
  const int rb = (xcd & 1) * 128 + (bid >> 3); // 0..255
  const f16* Wb = Wcat + (size_t)cb * 260 * 4096;
  const int rbase = wid * 64 + l31;            // + rt*32

  auto stageTo = [&](int c, char* dst) {
    const char* src = (const char*)(Wb + (size_t)c * 4096);
#pragma unroll
    for (int it = 0; it < 4; ++it) {
      int off = (it * 128 + tid) * 16;
      gload_lds16(src + off, dst + off);
    }
  };

  // prologue: stage a-tile (16 KB) + chunks 0,1
  {
    const char* aSrc = (const char*)(a16s + (size_t)rb * 8192);
#pragma unroll
    for (int it = 0; it < 8; ++it) {
      int off = (it * 128 + tid) * 16;
      gload_lds16(aSrc + off, (char*)sAa + off);
    }
  }
  char* p0 = (char*)&sB[0][0];
  char* p1 = (char*)&sB[1][0];
  char* p2 = (char*)&sB[2][0];
  stageTo(0, p0);
  stageTo(1, p1);
  asm volatile("s_waitcnt vmcnt(4)" ::: "memory");  // a-tile + chunk0 done
  __builtin_amdgcn_s_barrier();
  __builtin_amdgcn_sched_barrier(0);

  f32x16 acc[2][2];
#pragma unroll
  for (int i = 0; i < 2; ++i)
#pragma unroll
    for (int j = 0; j < 2; ++j)
#pragma unroll
      for (int r = 0; r < 16; ++r) acc[i][j][r] = 0.f;

  f16x8 xv[2][4];
  auto loadXV = [&](int er) {
#pragma unroll
    for (int rt = 0; rt < 2; ++rt)
#pragma unroll
      for (int ks = 0; ks < 4; ++ks) {
        const float* s = x + ((size_t)rb * 128 + rbase + rt * 32) * 256
                           + er * 64 + ks * 16 + khalf * 8;
        float4 u0 = *(const float4*)s;
        float4 u1 = *(const float4*)(s + 4);
        xv[rt][ks] = cvt8(u0, u1);
      }
  };

  // a-scalars: [g][row][8] -> byte (g*128+row)*16 ; conflict-free b128
  f16x8 as_cur[2], as_nxt[2];
#pragma unroll
  for (int rt = 0; rt < 2; ++rt)
    as_cur[rt] = *(const f16x8*)((const char*)sAa + (rbase + rt * 32) * 16);

  const int bOff = khalf * 1024 + l31 * 16;
  f16x8 bf[2][8];
#pragma unroll
  for (int ks = 0; ks < 4; ++ks)
#pragma unroll
    for (int ct = 0; ct < 2; ++ct)
      bf[0][ks * 2 + ct] = *(const f16x8*)(p0 + bOff + ks * 2048 + ct * 512);

  for (int q8 = 0; q8 < 256; q8 += 8) {
    int gn = ((q8 + 8) & 63) >> 3;   // next q8's a-group (wraps at er boundary)
#pragma unroll
    for (int rt = 0; rt < 2; ++rt)
      as_nxt[rt] = *(const f16x8*)((const char*)sAa + (gn * 128 + rbase + rt * 32) * 16);
    if ((q8 & 63) == 0) loadXV(q8 >> 6);
#pragma unroll
    for (int u = 0; u < 8; ++u) {
      const int q = q8 + u;
      stageTo(q + 2, p2);
      f16x8 af[2][4];                 // af(q): register-only, overlaps the wait
#pragma unroll
      for (int rt = 0; rt < 2; ++rt)
#pragma unroll
        for (int ks = 0; ks < 4; ++ks)
          af[rt][ks] = xv[rt][ks] * as_cur[rt][u];
      asm volatile("s_waitcnt vmcnt(4)" ::: "memory");  // chunk q+1 landed
      __builtin_amdgcn_s_barrier();
      __builtin_amdgcn_sched_barrier(0);
      const char* nb = p1 + bOff;     // prefetch bf(q+1), certified by barrier
#pragma unroll
      for (int ks = 0; ks < 4; ++ks)
#pragma unroll
        for (int ct = 0; ct < 2; ++ct)
          bf[(u + 1) & 1][ks * 2 + ct] = *(const f16x8*)(nb + ks * 2048 + ct * 512);
      __builtin_amdgcn_s_setprio(1);
#pragma unroll
      for (int ks = 0; ks < 4; ++ks)
#pragma unroll
        for (int rt = 0; rt < 2; ++rt)
#pragma unroll
          for (int ct = 0; ct < 2; ++ct)
            acc[rt][ct] = __builtin_amdgcn_mfma_f32_32x32x16_f16(
                af[rt][ks], bf[u & 1][ks * 2 + ct], acc[rt][ct], 0, 0, 0);
      __builtin_amdgcn_s_setprio(0);
      char* t = p0; p0 = p1; p1 = p2; p2 = t;
    }
    as_cur[0] = as_nxt[0];
    as_cur[1] = as_nxt[1];
  }

  // bias chunk (q=256): bf[0] prefetched at q=255; A = a[row,k] from sAa.
#pragma unroll
  for (int ks = 0; ks < 4; ++ks)
#pragma unroll
    for (int rt = 0; rt < 2; ++rt) {
      int g = ks * 2 + khalf;
      f16x8 af = *(const f16x8*)((const char*)sAa + (g * 128 + rbase + rt * 32) * 16);
#pragma unroll
      for (int ct = 0; ct < 2; ++ct)
        acc[rt][ct] = __builtin_amdgcn_mfma_f32_32x32x16_f16(
            af, bf[0][ks * 2 + ct], acc[rt][ct], 0, 0, 0);
    }

  // store: row = rb*128 + wid*64 + rt*32 + (r&3)+8*(r>>2)+4*khalf;
  //        col = cb*64 + ct*32 + l31
#pragma unroll
  for (int rt = 0; rt < 2; ++rt)
#pragma unroll
    for (int ct = 0; ct < 2; ++ct)
#pragma unroll
      for (int r = 0; r < 16; ++r) {
        int rowin = (r & 3) + 8 * (r >> 2) + 4 * khalf;
        size_t row = (size_t)rb * 128 + wid * 64 + rt * 32 + rowin;
        int col = cb * 64 + ct * 32 + l31;
        sel[row * 256 + col] = (f16)acc[rt][ct][r];
      }
}

// ---------------------------------------------------------------------------
extern "C" void kernel_launch(void* const* d_in, const int* in_sizes, int n_in,
                              void* d_out, int out_size, void* d_ws, size_t ws_size,
                              hipStream_t stream) {
  (void)in_sizes; (void)n_in; (void)out_size;
  const float* x   = (const float*)d_in[0];
  const float* ctx = (const float*)d_in[1];
  const float* Wm  = (const float*)d_in[2];
  const float* bm  = (const float*)d_in[3];
  const float* cm  = (const float*)d_in[4];
  const float* um  = (const float*)d_in[5];
  const float* vm  = (const float*)d_in[6];
  const float* W1  = (const float*)d_in[7];
  const float* b1  = (const float*)d_in[8];
  const float* W2  = (const float*)d_in[9];
  const float* b2  = (const float*)d_in[10];
  const float* Wi  = (const float*)d_in[11];
  const float* bi  = (const float*)d_in[12];
  float* out = (float*)d_out;

  char* ws = (char*)d_ws;
  size_t off = 0;
  // Wcat: 4 col-quarters x 260 sub-chunk slots x 8KB
  f16* Wcat = (f16*)(ws + off); off += (size_t)4 * 260 * 4096 * 2;
  f16* W1t  = (f16*)(ws + off); off += (size_t)512 * 256 * 2;
  f16* W2t  = (f16*)(ws + off); off += (size_t)64 * 512 * 2;
  f16* umt  = (f16*)(ws + off); off += (size_t)64 * 256 * 2;
  f16* Wit  = (f16*)(ws + off); off += (size_t)256 * 512 * 2;
  f16* h16  = (f16*)(ws + off); off += (size_t)32768 * 512 * 2;
  float* logits = (float*)(ws + off); off += (size_t)32768 * 64 * 4;
  float* glog   = (float*)(ws + off); off += (size_t)32768 * 64 * 4;
  f16* a16s  = (f16*)(ws + off); off += (size_t)32768 * 64 * 2;
  f16* sel16 = (f16*)(ws + off); off += (size_t)32768 * 256 * 2;
  if (ws_size < off) return;

  // ---- weight prep ----
  prep_wcat_kernel<<<dim3(2056), dim3(256), 0, stream>>>(Wm, bm, cm, Wcat);
  prep_b_kernel<<<dim3(16384 / 256), dim3(256), 0, stream>>>(W1, W1t, 256, 256, 16384);
  prep_b_kernel<<<dim3(4096 / 256),  dim3(256), 0, stream>>>(W2, W2t, 512, 64, 4096);
  prep_b_kernel<<<dim3(2048 / 256),  dim3(256), 0, stream>>>(um, umt, 256, 64, 2048);
  prep_b_kernel<<<dim3(16384 / 256), dim3(256), 0, stream>>>(Wi, Wit, 512, 256, 16384);

  // ---- phase A: selector ----
  gemm_tpl<256, 4, 4, 1><<<dim3(256, 2), dim3(512), 0, stream>>>(
      ctx, 256, nullptr, 0, W1t, b1, nullptr, h16, 512);
  gemm_tpl<64, 4, 4, 0><<<dim3(256, 1), dim3(256), 0, stream>>>(
      x, 256, nullptr, 0, umt, nullptr, glog, nullptr, 64);
  gemm_tpl<64, 8, 0, 0><<<dim3(256, 1), dim3(256), 0, stream>>>(
      nullptr, 0, h16, 512, W2t, nullptr, logits, nullptr, 64);
  selector_finish<<<dim3(32768 / 4), dim3(256), 0, stream>>>(logits, glog, b2, vm, a16s);

  // ---- phase B: the 275-TFLOP contraction ----
  big_gemm<<<dim3(1024), dim3(128), 0, stream>>>(x, a16s, Wcat, sel16);

  // ---- phase C: integrate([x, selected]) ----
  gemm_tpl<256, 8, 4, 0><<<dim3(256, 1), dim3(512), 0, stream>>>(
      x, 256, sel16, 256, Wit, bi, out, nullptr, 256);
}

// Round 8
// 351.048 us; speedup vs baseline: 1.0273x; 1.0273x over previous
//
#include <hip/hip_runtime.h>
#include <cstdint>
#include <cstddef>

// ============================================================================
// MechanismGrabber on MI355X (gfx950)
//
// selected[n,d] = sum_{m,e} a[n,m]*x[n,e]*Wm[m,d,e] + sum_m a[n,m]*(bm+cm)[m,d]
// == single GEMM: (N=32768) x (K=16448) x (D=256) with A generated on the fly.
//
// R7 = R6 with the compile fix (no LDS pointer array; single base + offsets):
//     BM=256 (4-wave blocks, tile 256x64) -> per-CU L2 staging demand halved;
//     chunk PAIRS per sync (1 barrier + 1 vmcnt(4) per 2 chunks, 32 MFMAs
//     between syncs); 3x16KB pair ring + 32KB a-tile = 80KB -> 2 blocks/CU;
//     stage issued after the barrier (race-free with pairing).
// ============================================================================

typedef _Float16 f16;
typedef f16 f16x8 __attribute__((ext_vector_type(8)));
typedef float f32x4 __attribute__((ext_vector_type(4)));
typedef float f32x16 __attribute__((ext_vector_type(16)));

#define DEV __device__ __forceinline__

DEV uint32_t swz128(uint32_t b) { return b ^ (((b >> 7) & 7u) << 4); }

DEV void gload_lds16(const void* g, void* l) {
  __builtin_amdgcn_global_load_lds(
      (const __attribute__((address_space(1))) unsigned int*)g,
      (__attribute__((address_space(3))) unsigned int*)l, 16, 0, 0);
}

DEV f16x8 cvt8(float4 u0, float4 u1) {
  f16x8 v = {(f16)u0.x, (f16)u0.y, (f16)u0.z, (f16)u0.w,
             (f16)u1.x, (f16)u1.y, (f16)u1.z, (f16)u1.w};
  return v;
}

// ---------------------------------------------------------------------------
// prep for gemm_tpl (16x16x32 path, selector/integrate): unchanged.
// ---------------------------------------------------------------------------
__global__ void prep_b_kernel(const float* __restrict__ S, f16* __restrict__ dst,
                              int K, int BN, int total) {
  int t = blockIdx.x * 256 + threadIdx.x;
  if (t >= total) return;
  int gpc = BN * 8;
  int g = t % gpc;
  int c = (t / gpc) % (K / 64);
  int cb = t / (gpc * (K / 64));
  int ks = g / (BN * 4);
  int rem = g % (BN * 4);
  int col = rem >> 2;
  int kg = rem & 3;
  int J = cb * BN + col;
  int k = c * 64 + ks * 32 + kg * 8;
  const float* s = S + (size_t)J * K + k;
  float4 u0 = *(const float4*)s;
  float4 u1 = *(const float4*)(s + 4);
  f16* chunk = dst + (size_t)(cb * (K / 64) + c) * (BN * 64);
  *(f16x8*)((char*)chunk + swz128((uint32_t)g * 16)) = cvt8(u0, u1);
}

// ---------------------------------------------------------------------------
// Wcat: [cb 0..3][c 0..259] sub-chunks of 64k x 64col = 8 KB (linear,
// conflict-free). group g = kstep*128 + khalf*64 + col64, byte g*16, holds
// B[k][col] for k = kstep*16 + khalf*8 + (0..7), col = cb*64 + col64.
// c<256: er=c>>6, m=c&63; value[k][col] = Wm[m][col][er*64+k].
// c==256: value[k][col] = bm[k][col]+cm[k][col].  c>=257: dummy.
// ---------------------------------------------------------------------------
__global__ void prep_wcat_kernel(const float* __restrict__ Wm,
                                 const float* __restrict__ bm,
                                 const float* __restrict__ cm,
                                 f16* __restrict__ dst) {
  int t = blockIdx.x * 256 + threadIdx.x;
  if (t >= 4 * 257 * 512) return;
  int g = t & 511;
  int gc = t >> 9;
  int c = gc % 257;
  int cb = gc / 257;
  int kstep = g >> 7;          // 0..3
  int khalf = (g >> 6) & 1;    // 0..1
  int col = cb * 64 + (g & 63);
  int k0 = kstep * 16 + khalf * 8;
  f16x8 v;
  if (c < 256) {
    int m = c & 63;
    int e0 = (c >> 6) * 64 + k0;
    const float* s = Wm + ((size_t)m * 256 + col) * 256 + e0;
    float4 u0 = *(const float4*)s;
    float4 u1 = *(const float4*)(s + 4);
    v = cvt8(u0, u1);
  } else {
#pragma unroll
    for (int j = 0; j < 8; ++j) {
      int k = k0 + j;
      v[j] = (f16)(bm[k * 256 + col] + cm[k * 256 + col]);
    }
  }
  *(f16x8*)(dst + ((size_t)(cb * 260 + c)) * 4096 + (size_t)g * 8) = v;
}

// ---------------------------------------------------------------------------
// Generic MFMA GEMM (selector + integrate phases). Unchanged.
// ---------------------------------------------------------------------------
template <int BN, int NCHUNK, int A0C, int EPI>
__global__ __launch_bounds__(BN == 256 ? 512 : 256, 2)
void gemm_tpl(const float* __restrict__ A0, int lda0,
              const f16* __restrict__ A1, int lda1,
              const f16* __restrict__ Bt,
              const float* __restrict__ bias,
              float* __restrict__ outF, f16* __restrict__ outH, int ldo) {
  constexpr int WAVES = (BN == 256) ? 8 : 4;
  constexpr int THREADS = WAVES * 64;
  constexpr int WC = (BN == 256) ? 4 : 1;
  constexpr int WR = WAVES / WC;
  constexpr int RT = 128 / (WR * 16);
  constexpr int CT = (BN / WC) / 16;

  __shared__ alignas(16) f16 sA[2][128 * 64];
  __shared__ alignas(16) f16 sB[2][BN * 64];

  const int tid = threadIdx.x;
  const int lane = tid & 63;
  const int wid = tid >> 6;
  const int wr = wid / WC, wc = wid % WC;
  const int rb = blockIdx.x, cb = blockIdx.y;

  auto stageB = [&](int c, int buf) {
    const char* src = (const char*)(Bt + (size_t)(cb * NCHUNK + c) * (BN * 64));
#pragma unroll
    for (int it = 0; it < (BN * 64 * 2) / (THREADS * 16); ++it) {
      int off = (it * THREADS + tid) * 16;
      gload_lds16(src + off, (char*)&sB[buf][0] + off);
    }
  };
  auto stageA = [&](int c, int buf) {
#pragma unroll
    for (int it = 0; it < 1024 / THREADS; ++it) {
      int gg = it * THREADS + tid;
      int row = gg >> 3, eg = gg & 7;
      size_t rowG = (size_t)rb * 128 + row;
      f16x8 v;
      if (A0C > 0 && c < A0C) {
        const float* s = A0 + rowG * lda0 + c * 64 + eg * 8;
        float4 u0 = *(const float4*)s;
        float4 u1 = *(const float4*)(s + 4);
        v = cvt8(u0, u1);
      } else {
        v = *(const f16x8*)(A1 + rowG * lda1 + (c - A0C) * 64 + eg * 8);
      }
      *(f16x8*)((char*)&sA[buf][0] + swz128((uint32_t)(row * 128 + eg * 16))) = v;
    }
  };

  f32x4 acc[RT][CT];
#pragma unroll
  for (int i = 0; i < RT; ++i)
#pragma unroll
    for (int j = 0; j < CT; ++j) acc[i][j] = (f32x4){0.f, 0.f, 0.f, 0.f};

  stageB(0, 0);
  stageA(0, 0);
  __syncthreads();

  for (int c = 0; c < NCHUNK; ++c) {
    int cur = c & 1;
    if (c + 1 < NCHUNK) {
      stageB(c + 1, cur ^ 1);
      stageA(c + 1, cur ^ 1);
    }
#pragma unroll
    for (int ks = 0; ks < 2; ++ks) {
      f16x8 af[RT], bf[CT];
#pragma unroll
      for (int rt = 0; rt < RT; ++rt) {
        int row = wr * (RT * 16) + rt * 16 + (lane & 15);
        af[rt] = *(const f16x8*)((const char*)&sA[cur][0] +
                                 swz128((uint32_t)(row * 128 + ks * 64 + (lane >> 4) * 16)));
      }
#pragma unroll
      for (int ct = 0; ct < CT; ++ct) {
        int col = wc * (CT * 16) + ct * 16 + (lane & 15);
        bf[ct] = *(const f16x8*)((const char*)&sB[cur][0] +
                                 swz128((uint32_t)(((ks * BN + col) * 4 + (lane >> 4)) * 16)));
      }
#pragma unroll
      for (int rt = 0; rt < RT; ++rt)
#pragma unroll
        for (int ct = 0; ct < CT; ++ct)
          acc[rt][ct] = __builtin_amdgcn_mfma_f32_16x16x32_f16(af[rt], bf[ct], acc[rt][ct], 0, 0, 0);
    }
    __syncthreads();
  }

#pragma unroll
  for (int rt = 0; rt < RT; ++rt)
#pragma unroll
    for (int ct = 0; ct < CT; ++ct)
#pragma unroll
      for (int i = 0; i < 4; ++i) {
        size_t row = (size_t)rb * 128 + wr * (RT * 16) + rt * 16 + (lane >> 4) * 4 + i;
        int colG = cb * BN + wc * (CT * 16) + ct * 16 + (lane & 15);
        float v = acc[rt][ct][i];
        if constexpr (EPI == 0) {
          if (bias) v += bias[colG];
          outF[row * ldo + colG] = v;
        } else {
          v += bias[colG];
          float ge = 0.5f * v * (1.0f + erff(v * 0.70710678118f));
          outH[row * ldo + colG] = (f16)ge;
        }
      }
}

// ---------------------------------------------------------------------------
// selector finish -> big_gemm staging layout:
// a16s[rb][g][row][j]  (rb = n>>8, row = n&255, m = g*8+j); 32KB per rb tile.
// ---------------------------------------------------------------------------
__global__ void selector_finish(const float* __restrict__ logits,
                                const float* __restrict__ glog,
                                const float* __restrict__ b2,
                                const float* __restrict__ vm,
                                f16* __restrict__ a16s) {
  int n = blockIdx.x * 4 + (threadIdx.x >> 6);
  int m = threadIdx.x & 63;
  float l = logits[(size_t)n * 64 + m] + b2[m];
  float mx = l;
#pragma unroll
  for (int o = 32; o; o >>= 1) mx = fmaxf(mx, __shfl_xor(mx, o));
  float p = expf(l - mx);
  float s = p;
#pragma unroll
  for (int o = 32; o; o >>= 1) s += __shfl_xor(s, o);
  float g = glog[(size_t)n * 64 + m] + vm[m];
  float gate = 1.0f / (1.0f + expf(-g));
  int rb = n >> 8, row = n & 255, gg = m >> 3, j = m & 7;
  a16s[(size_t)rb * 16384 + gg * 2048 + row * 8 + j] = (f16)(p / s * gate);
}

// ---------------------------------------------------------------------------
// big_gemm v6b: 256 threads (4 waves), tile 256x64, wave tile 64x64
// (32x32x16, rt=2, ct=2). 3x16KB pair-ring + 32KB a-tile = 80KB -> 2 blk/CU.
// Per pair-iter j: af(even) [reg-only] -> vmcnt(4) [pair j landed, own]
// -> barrier [all waves'] -> stage(pair j+2) -> ds_read bfA,bfB
// -> 16 MFMA(even) -> af(odd) -> 16 MFMA(odd).
// ---------------------------------------------------------------------------
__global__ __launch_bounds__(256, 2)
void big_gemm(const float* __restrict__ x, const f16* __restrict__ a16s,
              const f16* __restrict__ Wcat, f16* __restrict__ sel) {
  __shared__ alignas(16) f16 sB[3][128 * 64];    // 3 pair-slots x 16 KB
  __shared__ alignas(16) f16 sAa[8 * 256 * 8];   // 32 KB: [g][row 0..255][8m]

  const int tid = threadIdx.x;
  const int lane = tid & 63;
  const int wid = tid >> 6;        // 0..3 -> rows wid*64..+63
  const int l31 = lane & 31;
  const int khalf = lane >> 5;     // 0..1
  const int bid = blockIdx.x;
  const int xcd = bid & 7;
  const int cb = xcd >> 1;                      // col-quarter per XCD-pair
  const int rb = (xcd & 1) * 64 + (bid >> 3);   // 0..127 (256-row tiles)
  const f16* Wb = Wcat + (size_t)cb * 260 * 4096;
  const int rbase = wid * 64 + l31;             // + rt*32

  char* const sBbase = (char*)&sB[0][0];        // slot i at sBbase + i*16384

  auto stagePair = [&](int p, int slotIdx) {    // 16 KB (chunks 2p, 2p+1)
    const char* src = (const char*)Wb + (size_t)p * 16384;
    char* dst = sBbase + slotIdx * 16384;
#pragma unroll
    for (int it = 0; it < 4; ++it) {
      int off = (it * 256 + tid) * 16;
      gload_lds16(src + off, dst + off);
    }
  };

  // prologue: a-tile (32 KB) + pairs 0,1
  {
    const char* aSrc = (const char*)(a16s + (size_t)rb * 16384);
#pragma unroll
    for (int it = 0; it < 8; ++it) {
      int off = (it * 256 + tid) * 16;
      gload_lds16(aSrc + off, (char*)sAa + off);
    }
  }
  stagePair(0, 0);
  stagePair(1, 1);
  asm volatile("s_waitcnt vmcnt(4)" ::: "memory");  // a-tile + pair0 done
  __builtin_amdgcn_s_barrier();
  __builtin_amdgcn_sched_barrier(0);

  f32x16 acc[2][2];
#pragma unroll
  for (int i = 0; i < 2; ++i)
#pragma unroll
    for (int j = 0; j < 2; ++j)
#pragma unroll
      for (int r = 0; r < 16; ++r) acc[i][j][r] = 0.f;

  f16x8 xv[2][4];
  auto loadXV = [&](int er) {
#pragma unroll
    for (int rt = 0; rt < 2; ++rt)
#pragma unroll
      for (int ks = 0; ks < 4; ++ks) {
        const float* s = x + ((size_t)rb * 256 + rbase + rt * 32) * 256
                           + er * 64 + ks * 16 + khalf * 8;
        float4 u0 = *(const float4*)s;
        float4 u1 = *(const float4*)(s + 4);
        xv[rt][ks] = cvt8(u0, u1);
      }
  };

  const int bOff = khalf * 1024 + l31 * 16;   // + ks*2048 + ct*512 (+8192 odd)

  for (int q8g = 0; q8g < 32; ++q8g) {
    const int q8 = q8g * 8;
    if ((q8 & 63) == 0) loadXV(q8 >> 6);
    // a-scalars for these 8 chunks: [g][row][8] conflict-free b128
    f16x8 as_cur[2];
    {
      int g = (q8 & 63) >> 3;
#pragma unroll
      for (int rt = 0; rt < 2; ++rt)
        as_cur[rt] = *(const f16x8*)((const char*)sAa + ((g * 256) + rbase + rt * 32) * 16);
    }
#pragma unroll
    for (int p = 0; p < 4; ++p) {
      const int pj = (q8 >> 1) + p;             // pair index 0..127
      // af for the even chunk (register-only; overlaps the wait)
      f16x8 af0[2][4];
#pragma unroll
      for (int rt = 0; rt < 2; ++rt)
#pragma unroll
        for (int ks = 0; ks < 4; ++ks)
          af0[rt][ks] = xv[rt][ks] * as_cur[rt][2 * p + 0];
      asm volatile("s_waitcnt vmcnt(4)" ::: "memory");  // pair pj landed (own)
      __builtin_amdgcn_s_barrier();                      // ... all waves'
      __builtin_amdgcn_sched_barrier(0);
      stagePair(pj + 2, (pj + 2) % 3);                   // after barrier: race-free
      const char* base = sBbase + (pj % 3) * 16384 + bOff;
      f16x8 bfA[8], bfB[8];
#pragma unroll
      for (int ks = 0; ks < 4; ++ks)
#pragma unroll
        for (int ct = 0; ct < 2; ++ct) {
          bfA[ks * 2 + ct] = *(const f16x8*)(base + ks * 2048 + ct * 512);
          bfB[ks * 2 + ct] = *(const f16x8*)(base + 8192 + ks * 2048 + ct * 512);
        }
      __builtin_amdgcn_s_setprio(1);
#pragma unroll
      for (int ks = 0; ks < 4; ++ks)
#pragma unroll
        for (int rt = 0; rt < 2; ++rt)
#pragma unroll
          for (int ct = 0; ct < 2; ++ct)
            acc[rt][ct] = __builtin_amdgcn_mfma_f32_32x32x16_f16(
                af0[rt][ks], bfA[ks * 2 + ct], acc[rt][ct], 0, 0, 0);
      __builtin_amdgcn_s_setprio(0);
      // af for the odd chunk (VALU overlaps MFMA pipe)
      f16x8 af1[2][4];
#pragma unroll
      for (int rt = 0; rt < 2; ++rt)
#pragma unroll
        for (int ks = 0; ks < 4; ++ks)
          af1[rt][ks] = xv[rt][ks] * as_cur[rt][2 * p + 1];
      __builtin_amdgcn_s_setprio(1);
#pragma unroll
      for (int ks = 0; ks < 4; ++ks)
#pragma unroll
        for (int rt = 0; rt < 2; ++rt)
#pragma unroll
          for (int ct = 0; ct < 2; ++ct)
            acc[rt][ct] = __builtin_amdgcn_mfma_f32_32x32x16_f16(
                af1[rt][ks], bfB[ks * 2 + ct], acc[rt][ct], 0, 0, 0);
      __builtin_amdgcn_s_setprio(0);
    }
  }

  // bias chunk = even half of pair 128 (slot 128%3=2), staged at iter 126.
  asm volatile("s_waitcnt vmcnt(4)" ::: "memory");  // stage(128) landed (own)
  __builtin_amdgcn_s_barrier();                      // ... all waves'
#pragma unroll
  for (int ks = 0; ks < 4; ++ks)
#pragma unroll
    for (int rt = 0; rt < 2; ++rt) {
      int g = ks * 2 + khalf;
      f16x8 af = *(const f16x8*)((const char*)sAa + ((g * 256) + rbase + rt * 32) * 16);
#pragma unroll
      for (int ct = 0; ct < 2; ++ct) {
        f16x8 bf = *(const f16x8*)(sBbase + 2 * 16384 + bOff + ks * 2048 + ct * 512);
        acc[rt][ct] = __builtin_amdgcn_mfma_f32_32x32x16_f16(af, bf, acc[rt][ct], 0, 0, 0);
      }
    }

  // store: row = rb*256 + wid*64 + rt*32 + (r&3)+8*(r>>2)+4*khalf;
  //        col = cb*64 + ct*32 + l31
#pragma unroll
  for (int rt = 0; rt < 2; ++rt)
#pragma unroll
    for (int ct = 0; ct < 2; ++ct)
#pragma unroll
      for (int r = 0; r < 16; ++r) {
        int rowin = (r & 3) + 8 * (r >> 2) + 4 * khalf;
        size_t row = (size_t)rb * 256 + wid * 64 + rt * 32 + rowin;
        int col = cb * 64 + ct * 32 + l31;
        sel[row * 256 + col] = (f16)acc[rt][ct][r];
      }
}

// ---------------------------------------------------------------------------
extern "C" void kernel_launch(void* const* d_in, const int* in_sizes, int n_in,
                              void* d_out, int out_size, void* d_ws, size_t ws_size,
                              hipStream_t stream) {
  (void)in_sizes; (void)n_in; (void)out_size;
  const float* x   = (const float*)d_in[0];
  const float* ctx = (const float*)d_in[1];
  const float* Wm  = (const float*)d_in[2];
  const float* bm  = (const float*)d_in[3];
  const float* cm  = (const float*)d_in[4];
  const float* um  = (const float*)d_in[5];
  const float* vm  = (const float*)d_in[6];
  const float* W1  = (const float*)d_in[7];
  const float* b1  = (const float*)d_in[8];
  const float* W2  = (const float*)d_in[9];
  const float* b2  = (const float*)d_in[10];
  const float* Wi  = (const float*)d_in[11];
  const float* bi  = (const float*)d_in[12];
  float* out = (float*)d_out;

  char* ws = (char*)d_ws;
  size_t off = 0;
  // Wcat: 4 col-quarters x 260 sub-chunk slots x 8KB
  f16* Wcat = (f16*)(ws + off); off += (size_t)4 * 260 * 4096 * 2;
  f16* W1t  = (f16*)(ws + off); off += (size_t)512 * 256 * 2;
  f16* W2t  = (f16*)(ws + off); off += (size_t)64 * 512 * 2;
  f16* umt  = (f16*)(ws + off); off += (size_t)64 * 256 * 2;
  f16* Wit  = (f16*)(ws + off); off += (size_t)256 * 512 * 2;
  f16* h16  = (f16*)(ws + off); off += (size_t)32768 * 512 * 2;
  float* logits = (float*)(ws + off); off += (size_t)32768 * 64 * 4;
  float* glog   = (float*)(ws + off); off += (size_t)32768 * 64 * 4;
  f16* a16s  = (f16*)(ws + off); off += (size_t)32768 * 64 * 2;
  f16* sel16 = (f16*)(ws + off); off += (size_t)32768 * 256 * 2;
  if (ws_size < off) return;

  // ---- weight prep ----
  prep_wcat_kernel<<<dim3(2056), dim3(256), 0, stream>>>(Wm, bm, cm, Wcat);
  prep_b_kernel<<<dim3(16384 / 256), dim3(256), 0, stream>>>(W1, W1t, 256, 256, 16384);
  prep_b_kernel<<<dim3(4096 / 256),  dim3(256), 0, stream>>>(W2, W2t, 512, 64, 4096);
  prep_b_kernel<<<dim3(2048 / 256),  dim3(256), 0, stream>>>(um, umt, 256, 64, 2048);
  prep_b_kernel<<<dim3(16384 / 256), dim3(256), 0, stream>>>(Wi, Wit, 512, 256, 16384);

  // ---- phase A: selector ----
  gemm_tpl<256, 4, 4, 1><<<dim3(256, 2), dim3(512), 0, stream>>>(
      ctx, 256, nullptr, 0, W1t, b1, nullptr, h16, 512);
  gemm_tpl<64, 4, 4, 0><<<dim3(256, 1), dim3(256), 0, stream>>>(
      x, 256, nullptr, 0, umt, nullptr, glog, nullptr, 64);
  gemm_tpl<64, 8, 0, 0><<<dim3(256, 1), dim3(256), 0, stream>>>(
      nullptr, 0, h16, 512, W2t, nullptr, logits, nullptr, 64);
  selector_finish<<<dim3(32768 / 4), dim3(256), 0, stream>>>(logits, glog, b2, vm, a16s);

  // ---- phase B: the 275-TFLOP contraction ----
  big_gemm<<<dim3(512), dim3(256), 0, stream>>>(x, a16s, Wcat, sel16);

  // ---- phase C: integrate([x, selected]) ----
  gemm_tpl<256, 8, 4, 0><<<dim3(256, 1), dim3(512), 0, stream>>>(
      x, 256, sel16, 256, Wit, bi, out, nullptr, 256);
}